// Round 5
// baseline (158.880 us; speedup 1.0000x reference)
//
#include <hip/hip_runtime.h>
#include <stdint.h>

typedef unsigned long long u64;
typedef unsigned int u32;

#define NUM_TRAIN   50000
#define NUM_TEST    4096
#define CLASS_SIZE  5000
#define TT          8      // test samples per block in knn kernel
#define NCHUNK      4      // training-set chunks (grid = 2048 blocks)
#define CHUNK_ROWS  (NUM_TRAIN / NCHUNK)   // 12500

// ---------------------------------------------------------------------------
// Pack kernel: one wave per 256-int row; 4x __ballot -> 4 u64 (= 8 u32). Bit
// order is a fixed permutation (consistent train/test); XOR+popcount is
// permutation-invariant so Hamming distances are unchanged.
// ---------------------------------------------------------------------------
__global__ void pack_kernel(const int* __restrict__ train,
                            const int* __restrict__ test,
                            u64* __restrict__ packed) {
    int wave = (blockIdx.x * blockDim.x + threadIdx.x) >> 6;
    int lane = threadIdx.x & 63;
    const int* src = (wave < NUM_TRAIN)
                       ? (train + (size_t)wave * 256)
                       : (test + (size_t)(wave - NUM_TRAIN) * 256);
    int4 v = *reinterpret_cast<const int4*>(src + lane * 4);
    u64 b0 = __ballot(v.x & 1);
    u64 b1 = __ballot(v.y & 1);
    u64 b2 = __ballot(v.z & 1);
    u64 b3 = __ballot(v.w & 1);
    if (lane == 0) {
        u64* dst = packed + (size_t)wave * 4;
        dst[0] = b0; dst[1] = b1; dst[2] = b2; dst[3] = b3;
    }
}

// Sorted-insert key into (k0<=k1<=k2), keeping the 3 smallest. 5 VALU.
__device__ __forceinline__ void insert3(u32& k0, u32& k1, u32& k2, u32 key) {
    u32 m0 = min(k0, key);
    u32 m1 = min(k1, max(k0, key));
    u32 m2 = min(k2, max(k1, key));
    k0 = m0; k1 = m1; k2 = m2;
}

// Merge two sorted triples -> sorted top-3 of the union. 7 VALU.
__device__ __forceinline__ void merge3(u32& a0, u32& a1, u32& a2,
                                       u32 b0, u32 b1, u32 b2) {
    u32 hi0 = max(a0, b0);
    u32 lo1 = min(a1, b1);
    u32 c0  = min(a0, b0);
    u32 c1  = min(hi0, lo1);
    u32 c2  = min(max(lo1, hi0), min(a2, b2));
    a0 = c0; a1 = c1; a2 = c2;
}

// ---------------------------------------------------------------------------
// KNN kernel: block (g,c) = sample group g (TT=8 test rows, block-uniform ->
// SGPRs) x chunk c (12500 train rows). All-u32 hot loop: 8 v_xor + 8
// accumulating v_bcnt per pair. key = (dist<<16)|train_idx encodes the
// reference (dist, smaller-index) tie-break exactly.
// ---------------------------------------------------------------------------
__global__ __launch_bounds__(256) void knn_kernel(const u32* __restrict__ packed,
                                                  u32* __restrict__ partial) {
    const int g    = blockIdx.x >> 2;      // sample group (0..511)
    const int c    = blockIdx.x & 3;       // chunk (0..3)
    const int tid  = threadIdx.x;
    const int base = g * TT;
    const uint4* rows  = (const uint4*)packed;          // 2 uint4 per row
    const u32*  testp  = packed + (size_t)NUM_TRAIN * 8;

    u32 te[TT][8];   // block-uniform addresses -> compiler keeps these in SGPRs
    #pragma unroll
    for (int s = 0; s < TT; ++s) {
        const u32* p = testp + (size_t)(base + s) * 8;
        #pragma unroll
        for (int j = 0; j < 8; ++j) te[s][j] = p[j];
    }

    u32 k0[TT], k1[TT], k2[TT];
    #pragma unroll
    for (int s = 0; s < TT; ++s) { k0[s] = k1[s] = k2[s] = 0x7FFFFFFFu; }

    const int start = c * CHUNK_ROWS;
    const int end   = start + CHUNK_ROWS;
    for (int r = start + tid; r < end; r += 256) {
        uint4 a0 = rows[(size_t)r * 2];
        uint4 a1 = rows[(size_t)r * 2 + 1];
        #pragma unroll
        for (int s = 0; s < TT; ++s) {
            int d = __popc(a0.x ^ te[s][0]);
            d += __popc(a0.y ^ te[s][1]);
            d += __popc(a0.z ^ te[s][2]);
            d += __popc(a0.w ^ te[s][3]);
            d += __popc(a1.x ^ te[s][4]);
            d += __popc(a1.y ^ te[s][5]);
            d += __popc(a1.z ^ te[s][6]);
            d += __popc(a1.w ^ te[s][7]);
            u32 key = ((u32)d << 16) | (u32)r;
            insert3(k0[s], k1[s], k2[s], key);
        }
    }

    // Wave butterfly: top-3 merge is idempotent/commutative/associative,
    // so the xor-butterfly converges all 64 lanes to the wave-wide top-3.
    #pragma unroll
    for (int s = 0; s < TT; ++s) {
        for (int off = 1; off < 64; off <<= 1) {
            u32 o0 = __shfl_xor(k0[s], off);
            u32 o1 = __shfl_xor(k1[s], off);
            u32 o2 = __shfl_xor(k2[s], off);
            merge3(k0[s], k1[s], k2[s], o0, o1, o2);
        }
    }

    __shared__ u32 red[4][TT][3];
    const int wave = tid >> 6, lane = tid & 63;
    if (lane == 0) {
        #pragma unroll
        for (int s = 0; s < TT; ++s) {
            red[wave][s][0] = k0[s];
            red[wave][s][1] = k1[s];
            red[wave][s][2] = k2[s];
        }
    }
    __syncthreads();

    if (tid < TT) {
        const int s = tid;
        u32 a0 = red[0][s][0], a1 = red[0][s][1], a2 = red[0][s][2];
        #pragma unroll
        for (int w = 1; w < 4; ++w)
            merge3(a0, a1, a2, red[w][s][0], red[w][s][1], red[w][s][2]);
        u32* dst = partial + ((size_t)(base + s) * NCHUNK + c) * 3;
        dst[0] = a0; dst[1] = a1; dst[2] = a2;
    }
}

// ---------------------------------------------------------------------------
// Merge kernel: one thread per test sample; merge NCHUNK partial triples,
// derive labels, majority vote with argmax-first-max tie semantics.
// ---------------------------------------------------------------------------
__global__ __launch_bounds__(256) void merge_kernel(const u32* __restrict__ partial,
                                                    int* __restrict__ out) {
    int t = blockIdx.x * blockDim.x + threadIdx.x;
    if (t >= NUM_TEST) return;
    const u32* p = partial + (size_t)t * NCHUNK * 3;
    u32 a0 = p[0], a1 = p[1], a2 = p[2];
    #pragma unroll
    for (int c = 1; c < NCHUNK; ++c)
        merge3(a0, a1, a2, p[c * 3 + 0], p[c * 3 + 1], p[c * 3 + 2]);
    const int l0 = (int)(a0 & 0xFFFFu) / CLASS_SIZE;
    const int l1 = (int)(a1 & 0xFFFFu) / CLASS_SIZE;
    const int l2 = (int)(a2 & 0xFFFFu) / CLASS_SIZE;
    int winner;
    if (l0 == l1 || l0 == l2)      winner = l0;    // count(l0) >= 2
    else if (l1 == l2)             winner = l1;    // count(l1) == 2
    else winner = min(l0, min(l1, l2));            // 1-1-1: argmax picks first max
    out[t] = winner;
}

extern "C" void kernel_launch(void* const* d_in, const int* in_sizes, int n_in,
                              void* d_out, int out_size, void* d_ws, size_t ws_size,
                              hipStream_t stream) {
    const int* train = (const int*)d_in[0];
    const int* test  = (const int*)d_in[1];
    int* out = (int*)d_out;

    u64* packed = (u64*)d_ws;   // (50000+4096) rows * 32 B = 1.73 MB
    u32* partial = (u32*)((char*)d_ws + (size_t)(NUM_TRAIN + NUM_TEST) * 4 * sizeof(u64));
    // partial: 4096 * 4 * 3 * 4 B = 192 KB  (total ws use ~1.93 MB)

    const int total_rows = NUM_TRAIN + NUM_TEST;      // 54096, divisible by 4
    pack_kernel<<<total_rows / 4, 256, 0, stream>>>(train, test, packed);
    knn_kernel<<<(NUM_TEST / TT) * NCHUNK, 256, 0, stream>>>((const u32*)packed, partial);
    merge_kernel<<<(NUM_TEST + 255) / 256, 256, 0, stream>>>(partial, out);
}

// Round 6
// 155.005 us; speedup vs baseline: 1.0250x; 1.0250x over previous
//
#include <hip/hip_runtime.h>
#include <stdint.h>

typedef unsigned long long u64;
typedef unsigned int u32;
typedef int v4i  __attribute__((ext_vector_type(4)));
typedef int v16i __attribute__((ext_vector_type(16)));

#define NUM_TRAIN   50000
#define NUM_TEST    4096
#define CLASS_SIZE  5000

// ---- MFMA path geometry ----
#define TRAIN_PAD   50176              // 8 chunks * 4 waves * 49 tiles * 32 rows
#define KB          288                // 256 data dims + 4 trsum + 4 tesum + 24 pad
#define NCHUNK8     8                  // chunk = blockIdx&7 -> per-XCD L2 locality
#define WPB         4                  // waves per block
#define TILES_PER_WAVE 49
#define ROWS_PER_CHUNK (TRAIN_PAD / NCHUNK8)        // 6272
#define ROWS_PER_WAVE  (ROWS_PER_CHUNK / WPB)       // 1568

// ws layout (16.1 MB): train_i8 | test_i8 | partial8
#define OFF_TRAIN   0
#define SZ_TRAIN    ((size_t)TRAIN_PAD * KB)                    // 14,450,688
#define OFF_TEST    (OFF_TRAIN + SZ_TRAIN)
#define SZ_TEST     ((size_t)NUM_TEST * KB)                     // 1,179,648
#define OFF_PART8   (OFF_TEST + SZ_TEST)
#define SZ_PART8    ((size_t)NUM_TEST * NCHUNK8 * 3 * 4)        // 393,216
#define WS_NEEDED   (OFF_PART8 + SZ_PART8)

// ---------------------------------------------------------------------------
// Top-3 primitives (validated R2/R5). key = (dist<<16)|train_idx encodes the
// reference (dist asc, then smaller index) tie-break exactly.
// ---------------------------------------------------------------------------
__device__ __forceinline__ void insert3(u32& k0, u32& k1, u32& k2, u32 key) {
    u32 m0 = min(k0, key);
    u32 m1 = min(k1, max(k0, key));
    u32 m2 = min(k2, max(k1, key));
    k0 = m0; k1 = m1; k2 = m2;
}
__device__ __forceinline__ void merge3(u32& a0, u32& a1, u32& a2,
                                       u32 b0, u32 b1, u32 b2) {
    u32 hi0 = max(a0, b0);
    u32 lo1 = min(a1, b1);
    u32 c0  = min(a0, b0);
    u32 c1  = min(hi0, lo1);
    u32 c2  = min(max(lo1, hi0), min(a2, b2));
    a0 = c0; a1 = c1; a2 = c2;
}
__device__ __forceinline__ int wave_sum(int s) {
    #pragma unroll
    for (int off = 1; off < 64; off <<= 1) s += __shfl_xor(s, off);
    return s;
}

// ---------------------------------------------------------------------------
// pack_train_i8: one wave per row. Data byte k = -2*bit (i8 0xFE/0x00) so the
// MFMA picks up -2*inner. Tail dims: [256..259]=tr_sum split in 4 chunks<=127
// (x test-side 1), [260..263]=1 (x test-side te_sum chunks), rest 0.
// Pad rows (>=50000): data 0, chunks 127*4 -> dist >= 508 > any real dist.
// ---------------------------------------------------------------------------
__global__ __launch_bounds__(256) void pack_train_i8(const int* __restrict__ train,
                                                     char* __restrict__ dst) {
    int r    = (blockIdx.x * blockDim.x + threadIdx.x) >> 6;   // row (< TRAIN_PAD)
    int lane = threadIdx.x & 63;
    int4 v = make_int4(0, 0, 0, 0);
    if (r < NUM_TRAIN) v = *reinterpret_cast<const int4*>(train + (size_t)r * 256 + lane * 4);
    u32 w = (u32)((-2 * v.x) & 0xFF)
          | ((u32)((-2 * v.y) & 0xFF) << 8)
          | ((u32)((-2 * v.z) & 0xFF) << 16)
          | ((u32)((-2 * v.w) & 0xFF) << 24);
    *reinterpret_cast<u32*>(dst + (size_t)r * KB + lane * 4) = w;

    int total = wave_sum(v.x + v.y + v.z + v.w);               // row popcount
    if (lane < 8) {
        u32 tail = 0;
        if (lane == 0) {
            u32 c = (u32)(total >> 2), c3 = (u32)(total - 3 * (total >> 2));
            if (r >= NUM_TRAIN) { c = 127u; c3 = 127u; }
            tail = c | (c << 8) | (c << 16) | (c3 << 24);
        } else if (lane == 1) {
            tail = 0x01010101u;                                // a=1 at te_sum dims
        }
        *reinterpret_cast<u32*>(dst + (size_t)r * KB + 256 + lane * 4) = tail;
    }
}

// pack_test_i8: data byte = bit (0/1); [256..259]=1 (b=1 at tr_sum dims);
// [260..263]=te_sum chunks; rest 0.
__global__ __launch_bounds__(256) void pack_test_i8(const int* __restrict__ test,
                                                    char* __restrict__ dst) {
    int r    = (blockIdx.x * blockDim.x + threadIdx.x) >> 6;   // row (< NUM_TEST)
    int lane = threadIdx.x & 63;
    int4 v = *reinterpret_cast<const int4*>(test + (size_t)r * 256 + lane * 4);
    u32 w = (u32)v.x | ((u32)v.y << 8) | ((u32)v.z << 16) | ((u32)v.w << 24);
    *reinterpret_cast<u32*>(dst + (size_t)r * KB + lane * 4) = w;

    int total = wave_sum(v.x + v.y + v.z + v.w);
    if (lane < 8) {
        u32 tail = 0;
        if (lane == 0) {
            tail = 0x01010101u;                                // b=1 at tr_sum dims
        } else if (lane == 1) {
            u32 c = (u32)(total >> 2), c3 = (u32)(total - 3 * (total >> 2));
            tail = c | (c << 8) | (c << 16) | (c3 << 24);
        }
        *reinterpret_cast<u32*>(dst + (size_t)r * KB + 256 + lane * 4) = tail;
    }
}

// ---------------------------------------------------------------------------
// mfma_knn: block (tile = bid>>3, chunk = bid&7). 4 waves each sweep 49 train
// tiles of 32 rows; per tile 9x mfma_i32_32x32x32_i8 accumulate the FULL
// distance (sums folded into K dims, C seeded with zero). C/D layout
// (HW-verified): col = lane&31 (test col, fixed per lane -> private top-3),
// row = (g&3)+8*(g>>2)+4*(lane>>5). chunk==blockIdx%8 -> chunk data stays in
// one XCD's L2 (1.8 MB/chunk + 1.2 MB test < 4 MB).
// ---------------------------------------------------------------------------
__global__ __launch_bounds__(256) void mfma_knn(const char* __restrict__ A,
                                                const char* __restrict__ Bt,
                                                u32* __restrict__ partial) {
    const int chunk = blockIdx.x & 7;
    const int tile  = blockIdx.x >> 3;
    const int wid   = threadIdx.x >> 6;
    const int lane  = threadIdx.x & 63;
    const int col   = lane & 31;
    const int kh    = lane >> 5;

    // B fragments (test tile) held in registers: 9 steps x 16 B
    v4i bfrag[9];
    const char* bp = Bt + (size_t)(tile * 32 + col) * KB + kh * 16;
    #pragma unroll
    for (int kk = 0; kk < 9; ++kk)
        bfrag[kk] = *reinterpret_cast<const v4i*>(bp + kk * 32);

    const int rowbase = chunk * ROWS_PER_CHUNK + wid * ROWS_PER_WAVE;
    const char* ap = A + (size_t)(rowbase + col) * KB + kh * 16;

    const v16i zero16 = {0,0,0,0,0,0,0,0,0,0,0,0,0,0,0,0};
    u32 k0 = 0x7FFFFFFFu, k1 = 0x7FFFFFFFu, k2 = 0x7FFFFFFFu;
    int tb2 = rowbase + 4 * kh;            // + t*32 + rowconst(g) = train idx

    for (int t = 0; t < TILES_PER_WAVE; ++t) {
        v4i af0 = *reinterpret_cast<const v4i*>(ap);
        v16i acc = __builtin_amdgcn_mfma_i32_32x32x32_i8(af0, bfrag[0], zero16, 0, 0, 0);
        #pragma unroll
        for (int kk = 1; kk < 9; ++kk) {
            v4i af = *reinterpret_cast<const v4i*>(ap + kk * 32);
            acc = __builtin_amdgcn_mfma_i32_32x32x32_i8(af, bfrag[kk], acc, 0, 0, 0);
        }
        #pragma unroll
        for (int g = 0; g < 16; ++g) {
            const int row = (g & 3) + 8 * (g >> 2);            // compile-time
            u32 key = ((u32)acc[g] << 16) + (u32)(tb2 + row);
            insert3(k0, k1, k2, key);
        }
        tb2 += 32;
        ap  += 32 * KB;
    }

    // lanes l and l+32 hold complementary row-halves of the same test col
    u32 o0 = __shfl_xor(k0, 32), o1 = __shfl_xor(k1, 32), o2 = __shfl_xor(k2, 32);
    merge3(k0, k1, k2, o0, o1, o2);

    __shared__ u32 red[WPB][32][3];
    if (lane < 32) { red[wid][lane][0] = k0; red[wid][lane][1] = k1; red[wid][lane][2] = k2; }
    __syncthreads();
    if (threadIdx.x < 32) {
        const int c = threadIdx.x;
        u32 a0 = red[0][c][0], a1 = red[0][c][1], a2 = red[0][c][2];
        #pragma unroll
        for (int w = 1; w < WPB; ++w)
            merge3(a0, a1, a2, red[w][c][0], red[w][c][1], red[w][c][2]);
        u32* dst = partial + ((size_t)(tile * 32 + c) * NCHUNK8 + chunk) * 3;
        dst[0] = a0; dst[1] = a1; dst[2] = a2;
    }
}

// Vote kernel: merge NCHUNK8 partial triples per sample; majority vote with
// argmax-first-max tie semantics (validated R2/R5).
__global__ __launch_bounds__(256) void vote_kernel8(const u32* __restrict__ partial,
                                                    int* __restrict__ out) {
    int t = blockIdx.x * blockDim.x + threadIdx.x;
    if (t >= NUM_TEST) return;
    const u32* p = partial + (size_t)t * NCHUNK8 * 3;
    u32 a0 = p[0], a1 = p[1], a2 = p[2];
    #pragma unroll
    for (int c = 1; c < NCHUNK8; ++c)
        merge3(a0, a1, a2, p[c * 3 + 0], p[c * 3 + 1], p[c * 3 + 2]);
    const int l0 = (int)(a0 & 0xFFFFu) / CLASS_SIZE;
    const int l1 = (int)(a1 & 0xFFFFu) / CLASS_SIZE;
    const int l2 = (int)(a2 & 0xFFFFu) / CLASS_SIZE;
    int winner;
    if (l0 == l1 || l0 == l2)      winner = l0;
    else if (l1 == l2)             winner = l1;
    else winner = min(l0, min(l1, l2));
    out[t] = winner;
}

// ======================= validated R5 fallback path ========================
#define TT          8
#define NCHUNK      4
#define CHUNK_ROWS  (NUM_TRAIN / NCHUNK)

__global__ void pack_kernel(const int* __restrict__ train,
                            const int* __restrict__ test,
                            u64* __restrict__ packed) {
    int wave = (blockIdx.x * blockDim.x + threadIdx.x) >> 6;
    int lane = threadIdx.x & 63;
    const int* src = (wave < NUM_TRAIN)
                       ? (train + (size_t)wave * 256)
                       : (test + (size_t)(wave - NUM_TRAIN) * 256);
    int4 v = *reinterpret_cast<const int4*>(src + lane * 4);
    u64 b0 = __ballot(v.x & 1);
    u64 b1 = __ballot(v.y & 1);
    u64 b2 = __ballot(v.z & 1);
    u64 b3 = __ballot(v.w & 1);
    if (lane == 0) {
        u64* dst = packed + (size_t)wave * 4;
        dst[0] = b0; dst[1] = b1; dst[2] = b2; dst[3] = b3;
    }
}

__global__ __launch_bounds__(256) void knn_kernel(const u32* __restrict__ packed,
                                                  u32* __restrict__ partial) {
    const int g    = blockIdx.x >> 2;
    const int c    = blockIdx.x & 3;
    const int tid  = threadIdx.x;
    const int base = g * TT;
    const uint4* rows  = (const uint4*)packed;
    const u32*  testp  = packed + (size_t)NUM_TRAIN * 8;

    u32 te[TT][8];
    #pragma unroll
    for (int s = 0; s < TT; ++s) {
        const u32* p = testp + (size_t)(base + s) * 8;
        #pragma unroll
        for (int j = 0; j < 8; ++j) te[s][j] = p[j];
    }
    u32 k0[TT], k1[TT], k2[TT];
    #pragma unroll
    for (int s = 0; s < TT; ++s) { k0[s] = k1[s] = k2[s] = 0x7FFFFFFFu; }

    const int start = c * CHUNK_ROWS;
    const int end   = start + CHUNK_ROWS;
    for (int r = start + tid; r < end; r += 256) {
        uint4 a0 = rows[(size_t)r * 2];
        uint4 a1 = rows[(size_t)r * 2 + 1];
        #pragma unroll
        for (int s = 0; s < TT; ++s) {
            int d = __popc(a0.x ^ te[s][0]);
            d += __popc(a0.y ^ te[s][1]);
            d += __popc(a0.z ^ te[s][2]);
            d += __popc(a0.w ^ te[s][3]);
            d += __popc(a1.x ^ te[s][4]);
            d += __popc(a1.y ^ te[s][5]);
            d += __popc(a1.z ^ te[s][6]);
            d += __popc(a1.w ^ te[s][7]);
            u32 key = ((u32)d << 16) | (u32)r;
            insert3(k0[s], k1[s], k2[s], key);
        }
    }
    #pragma unroll
    for (int s = 0; s < TT; ++s) {
        for (int off = 1; off < 64; off <<= 1) {
            u32 o0 = __shfl_xor(k0[s], off);
            u32 o1 = __shfl_xor(k1[s], off);
            u32 o2 = __shfl_xor(k2[s], off);
            merge3(k0[s], k1[s], k2[s], o0, o1, o2);
        }
    }
    __shared__ u32 red[4][TT][3];
    const int wave = tid >> 6, lane = tid & 63;
    if (lane == 0) {
        #pragma unroll
        for (int s = 0; s < TT; ++s) {
            red[wave][s][0] = k0[s];
            red[wave][s][1] = k1[s];
            red[wave][s][2] = k2[s];
        }
    }
    __syncthreads();
    if (tid < TT) {
        const int s = tid;
        u32 a0 = red[0][s][0], a1 = red[0][s][1], a2 = red[0][s][2];
        #pragma unroll
        for (int w = 1; w < 4; ++w)
            merge3(a0, a1, a2, red[w][s][0], red[w][s][1], red[w][s][2]);
        u32* dst = partial + ((size_t)(base + s) * NCHUNK + c) * 3;
        dst[0] = a0; dst[1] = a1; dst[2] = a2;
    }
}

__global__ __launch_bounds__(256) void merge_kernel(const u32* __restrict__ partial,
                                                    int* __restrict__ out) {
    int t = blockIdx.x * blockDim.x + threadIdx.x;
    if (t >= NUM_TEST) return;
    const u32* p = partial + (size_t)t * NCHUNK * 3;
    u32 a0 = p[0], a1 = p[1], a2 = p[2];
    #pragma unroll
    for (int c = 1; c < NCHUNK; ++c)
        merge3(a0, a1, a2, p[c * 3 + 0], p[c * 3 + 1], p[c * 3 + 2]);
    const int l0 = (int)(a0 & 0xFFFFu) / CLASS_SIZE;
    const int l1 = (int)(a1 & 0xFFFFu) / CLASS_SIZE;
    const int l2 = (int)(a2 & 0xFFFFu) / CLASS_SIZE;
    int winner;
    if (l0 == l1 || l0 == l2)      winner = l0;
    else if (l1 == l2)             winner = l1;
    else winner = min(l0, min(l1, l2));
    out[t] = winner;
}
// ===========================================================================

extern "C" void kernel_launch(void* const* d_in, const int* in_sizes, int n_in,
                              void* d_out, int out_size, void* d_ws, size_t ws_size,
                              hipStream_t stream) {
    const int* train = (const int*)d_in[0];
    const int* test  = (const int*)d_in[1];
    int* out = (int*)d_out;

    if (ws_size >= WS_NEEDED) {
        char* train_i8 = (char*)d_ws + OFF_TRAIN;
        char* test_i8  = (char*)d_ws + OFF_TEST;
        u32*  partial  = (u32*)((char*)d_ws + OFF_PART8);

        pack_train_i8<<<TRAIN_PAD / 4, 256, 0, stream>>>(train, train_i8);
        pack_test_i8<<<NUM_TEST / 4, 256, 0, stream>>>(test, test_i8);
        mfma_knn<<<(NUM_TEST / 32) * NCHUNK8, 256, 0, stream>>>(train_i8, test_i8, partial);
        vote_kernel8<<<(NUM_TEST + 255) / 256, 256, 0, stream>>>(partial, out);
    } else {
        // validated R5 path (1.93 MB ws)
        u64* packed = (u64*)d_ws;
        u32* partial = (u32*)((char*)d_ws + (size_t)(NUM_TRAIN + NUM_TEST) * 4 * sizeof(u64));
        const int total_rows = NUM_TRAIN + NUM_TEST;
        pack_kernel<<<total_rows / 4, 256, 0, stream>>>(train, test, packed);
        knn_kernel<<<(NUM_TEST / TT) * NCHUNK, 256, 0, stream>>>((const u32*)packed, partial);
        merge_kernel<<<(NUM_TEST + 255) / 256, 256, 0, stream>>>(partial, out);
    }
}

// Round 9
// 104.997 us; speedup vs baseline: 1.5132x; 1.4763x over previous
//
#include <hip/hip_runtime.h>
#include <stdint.h>

typedef unsigned long long u64;
typedef unsigned int u32;
typedef int v4i  __attribute__((ext_vector_type(4)));
typedef int v16i __attribute__((ext_vector_type(16)));

#define NUM_TRAIN   50000
#define NUM_TEST    4096
#define CLASS_SIZE  5000
#define TRAIN_PAD   50176              // 1568 tiles of 32 rows
#define TOT_TILES   1568

// ws layout: train_i8 | test_i8 | te_sum | partial
#define SZ_TRAIN   ((size_t)TRAIN_PAD * 256)          // 12,845,056
#define SZ_TEST    ((size_t)NUM_TEST * 256)           //  1,048,576
#define SZ_TESUM   ((size_t)NUM_TEST * 4)             //     16,384
#define OFF_TEST   (SZ_TRAIN)
#define OFF_TESUM  (OFF_TEST + SZ_TEST)
#define OFF_PART   (OFF_TESUM + SZ_TESUM)             // 13,910,016
#define WS_NEED(NCH) (OFF_PART + (size_t)NUM_TEST * (NCH) * 3 * 4)

// ---------------------------------------------------------------------------
// Top-3 primitives (validated R2/R5/R6). key = (dist<<16)+train_idx encodes
// the reference (dist asc, then smaller index) tie-break exactly.
// ---------------------------------------------------------------------------
__device__ __forceinline__ void insert3(u32& k0, u32& k1, u32& k2, u32 key) {
    u32 m0 = min(k0, key);
    u32 m1 = min(k1, max(k0, key));
    u32 m2 = min(k2, max(k1, key));
    k0 = m0; k1 = m1; k2 = m2;
}
__device__ __forceinline__ void merge3(u32& a0, u32& a1, u32& a2,
                                       u32 b0, u32 b1, u32 b2) {
    u32 hi0 = max(a0, b0);
    u32 lo1 = min(a1, b1);
    u32 c0  = min(a0, b0);
    u32 c1  = min(hi0, lo1);
    u32 c2  = min(max(lo1, hi0), min(a2, b2));
    a0 = c0; a1 = c1; a2 = c2;
}
__device__ __forceinline__ int wave_sum(int s) {
    #pragma unroll
    for (int off = 1; off < 64; off <<= 1) s += __shfl_xor(s, off);
    return s;
}

// ---------------------------------------------------------------------------
// pack_train_bits: A byte = bit (0/1), 256 B/row. Pad rows (>=50000) zero.
// ---------------------------------------------------------------------------
__global__ __launch_bounds__(256) void pack_train_bits(const int* __restrict__ train,
                                                       char* __restrict__ dst) {
    int r    = (blockIdx.x * 256 + threadIdx.x) >> 6;
    int lane = threadIdx.x & 63;
    int4 v = make_int4(0, 0, 0, 0);
    if (r < NUM_TRAIN) v = *reinterpret_cast<const int4*>(train + (size_t)r * 256 + lane * 4);
    u32 w = (u32)(v.x & 1) | ((u32)(v.y & 1) << 8)
          | ((u32)(v.z & 1) << 16) | ((u32)(v.w & 1) << 24);
    *reinterpret_cast<u32*>(dst + (size_t)r * 256 + lane * 4) = w;
}

// pack_test_pm1: B byte = 1-2*bit (+1/-1); also writes te_sum[row].
__global__ __launch_bounds__(256) void pack_test_pm1(const int* __restrict__ test,
                                                     char* __restrict__ dst,
                                                     int* __restrict__ tesum) {
    int r    = (blockIdx.x * 256 + threadIdx.x) >> 6;
    int lane = threadIdx.x & 63;
    int4 v = *reinterpret_cast<const int4*>(test + (size_t)r * 256 + lane * 4);
    u32 w = (u32)((1 - 2 * v.x) & 0xFF) | ((u32)((1 - 2 * v.y) & 0xFF) << 8)
          | ((u32)((1 - 2 * v.z) & 0xFF) << 16) | ((u32)((1 - 2 * v.w) & 0xFF) << 24);
    *reinterpret_cast<u32*>(dst + (size_t)r * 256 + lane * 4) = w;
    int total = wave_sum(v.x + v.y + v.z + v.w);
    if (lane == 0) tesum[r] = total;
}

// ---------------------------------------------------------------------------
// mfma_knn: block (cg = bid/NCH, c = bid%NCH). 4 waves share one 32-row
// A-tile in LDS; each wave owns 32 test cols (B-frags + te_sum in regs).
// Staging is TRANSPARENT reg->ds_write (no global_load_lds): thread t loads
// A[row=t>>3][(t&7)*32 .. +32) and writes LDS[(t&7)*1024 + (t>>3)*32], so a
// lane's ds_read_b128 at col*32+kh*16+kk*1024 equals the R6-validated
// fragment A[col][kh*16+kk*32 .. +16). T14 split: loads for tile t+1 issued
// before compute(t); ds_write after the read barrier.
// acc = tr_sum - 2*inner; dist = acc + te_sum folded into the key base.
// Guarded epilogue nulls pad rows (idx >= 50000) on boundary tiles only.
// ---------------------------------------------------------------------------
template<int NCH>
__global__ __launch_bounds__(256) void mfma_knn(const char* __restrict__ A,
                                                const char* __restrict__ Bt,
                                                const int* __restrict__ tesum,
                                                u32* __restrict__ partial) {
    constexpr int TILES  = TOT_TILES / NCH;    // 28 (NCH=56) or 49 (NCH=32)
    constexpr int CHROWS = TRAIN_PAD / NCH;    // 896 or 1568
    const int cg   = blockIdx.x / NCH;
    const int c    = blockIdx.x % NCH;
    const int tid  = threadIdx.x;
    const int wid  = tid >> 6;
    const int lane = tid & 63;
    const int col  = lane & 31;
    const int kh   = lane >> 5;

    // B fragments: this wave's 32 test cols, 8 K-steps, held in registers.
    const int mycol = cg * 128 + wid * 32 + col;
    const char* bp = Bt + (size_t)mycol * 256 + kh * 16;
    v4i bfrag[8];
    #pragma unroll
    for (int kk = 0; kk < 8; ++kk)
        bfrag[kk] = *reinterpret_cast<const v4i*>(bp + kk * 32);
    const u32 base16 = ((u32)tesum[mycol] << 16);   // te_sum folded into key

    __shared__ char lds[8192];
    const char* chunkbase = A + (size_t)c * CHROWS * 256;
    const char* gsrc0 = chunkbase + (tid >> 3) * 256 + (tid & 7) * 32;
    char* lDst = &lds[(tid & 7) * 1024 + (tid >> 3) * 32];

    u32 k0 = 0x7FFFFFFFu, k1 = 0x7FFFFFFFu, k2 = 0x7FFFFFFFu;

    // prologue: stage tile 0
    uint4 s0 = *reinterpret_cast<const uint4*>(gsrc0);
    uint4 s1 = *reinterpret_cast<const uint4*>(gsrc0 + 16);
    *reinterpret_cast<uint4*>(lDst)      = s0;
    *reinterpret_cast<uint4*>(lDst + 16) = s1;
    __syncthreads();

    const char* lbase = &lds[0] + col * 32 + kh * 16;

    for (int t = 0; t < TILES; ++t) {
        if (t + 1 < TILES) {               // issue next-tile loads early (T14)
            const char* g = gsrc0 + (size_t)(t + 1) * 8192;
            s0 = *reinterpret_cast<const uint4*>(g);
            s1 = *reinterpret_cast<const uint4*>(g + 16);
        }
        v16i acc = {0,0,0,0,0,0,0,0,0,0,0,0,0,0,0,0};
        #pragma unroll
        for (int kk = 0; kk < 8; ++kk) {
            v4i af = *reinterpret_cast<const v4i*>(lbase + kk * 1024);
            acc = __builtin_amdgcn_mfma_i32_32x32x32_i8(af, bfrag[kk], acc, 0, 0, 0);
        }
        const int tbase   = c * CHROWS + t * 32;
        const u32 keybase = base16 + (u32)(tbase + 4 * kh);
        if (tbase + 32 <= NUM_TRAIN) {               // uniform fast path
            #pragma unroll
            for (int g = 0; g < 16; ++g) {
                const int row = (g & 3) + 8 * (g >> 2);
                u32 key = ((u32)acc[g] << 16) + keybase + (u32)row;
                insert3(k0, k1, k2, key);
            }
        } else {                                     // boundary/pad tiles only
            #pragma unroll
            for (int g = 0; g < 16; ++g) {
                const int row = (g & 3) + 8 * (g >> 2);
                const int idx = tbase + 4 * kh + row;
                u32 key = (idx < NUM_TRAIN)
                            ? (((u32)acc[g] << 16) + keybase + (u32)row)
                            : 0xFFFFFFFFu;
                insert3(k0, k1, k2, key);
            }
        }
        __syncthreads();                   // all waves done reading LDS(t)
        if (t + 1 < TILES) {
            *reinterpret_cast<uint4*>(lDst)      = s0;
            *reinterpret_cast<uint4*>(lDst + 16) = s1;
        }
        __syncthreads();                   // LDS holds tile t+1
    }

    // lanes l / l+32 hold complementary row-halves of the same test col
    u32 o0 = __shfl_xor(k0, 32), o1 = __shfl_xor(k1, 32), o2 = __shfl_xor(k2, 32);
    merge3(k0, k1, k2, o0, o1, o2);
    if (kh == 0) {
        u32* dst = partial + ((size_t)mycol * NCH + c) * 3;
        dst[0] = k0; dst[1] = k1; dst[2] = k2;
    }
}

// Vote kernel: merge NCH partial triples per sample; majority vote with
// argmax-first-max tie semantics (validated R2/R5/R6).
template<int NCH>
__global__ __launch_bounds__(256) void vote_knn(const u32* __restrict__ partial,
                                                int* __restrict__ out) {
    int t = blockIdx.x * 256 + threadIdx.x;
    if (t >= NUM_TEST) return;
    const u32* p = partial + (size_t)t * NCH * 3;
    u32 a0 = p[0], a1 = p[1], a2 = p[2];
    for (int c = 1; c < NCH; ++c)
        merge3(a0, a1, a2, p[c * 3 + 0], p[c * 3 + 1], p[c * 3 + 2]);
    const int l0 = (int)(a0 & 0xFFFFu) / CLASS_SIZE;
    const int l1 = (int)(a1 & 0xFFFFu) / CLASS_SIZE;
    const int l2 = (int)(a2 & 0xFFFFu) / CLASS_SIZE;
    int winner;
    if (l0 == l1 || l0 == l2)      winner = l0;
    else if (l1 == l2)             winner = l1;
    else winner = min(l0, min(l1, l2));
    out[t] = winner;
}

// ======================= validated R5 fallback path ========================
#define TT          8
#define NCHUNK      4
#define CHUNK_ROWS  (NUM_TRAIN / NCHUNK)

__global__ void pack_kernel(const int* __restrict__ train,
                            const int* __restrict__ test,
                            u64* __restrict__ packed) {
    int wave = (blockIdx.x * blockDim.x + threadIdx.x) >> 6;
    int lane = threadIdx.x & 63;
    const int* src = (wave < NUM_TRAIN)
                       ? (train + (size_t)wave * 256)
                       : (test + (size_t)(wave - NUM_TRAIN) * 256);
    int4 v = *reinterpret_cast<const int4*>(src + lane * 4);
    u64 b0 = __ballot(v.x & 1);
    u64 b1 = __ballot(v.y & 1);
    u64 b2 = __ballot(v.z & 1);
    u64 b3 = __ballot(v.w & 1);
    if (lane == 0) {
        u64* dst = packed + (size_t)wave * 4;
        dst[0] = b0; dst[1] = b1; dst[2] = b2; dst[3] = b3;
    }
}

__global__ __launch_bounds__(256) void knn_kernel(const u32* __restrict__ packed,
                                                  u32* __restrict__ partial) {
    const int g    = blockIdx.x >> 2;
    const int c    = blockIdx.x & 3;
    const int tid  = threadIdx.x;
    const int base = g * TT;
    const uint4* rows  = (const uint4*)packed;
    const u32*  testp  = packed + (size_t)NUM_TRAIN * 8;

    u32 te[TT][8];
    #pragma unroll
    for (int s = 0; s < TT; ++s) {
        const u32* p = testp + (size_t)(base + s) * 8;
        #pragma unroll
        for (int j = 0; j < 8; ++j) te[s][j] = p[j];
    }
    u32 k0[TT], k1[TT], k2[TT];
    #pragma unroll
    for (int s = 0; s < TT; ++s) { k0[s] = k1[s] = k2[s] = 0x7FFFFFFFu; }

    const int start = c * CHUNK_ROWS;
    const int end   = start + CHUNK_ROWS;
    for (int r = start + tid; r < end; r += 256) {
        uint4 a0 = rows[(size_t)r * 2];
        uint4 a1 = rows[(size_t)r * 2 + 1];
        #pragma unroll
        for (int s = 0; s < TT; ++s) {
            int d = __popc(a0.x ^ te[s][0]);
            d += __popc(a0.y ^ te[s][1]);
            d += __popc(a0.z ^ te[s][2]);
            d += __popc(a0.w ^ te[s][3]);
            d += __popc(a1.x ^ te[s][4]);
            d += __popc(a1.y ^ te[s][5]);
            d += __popc(a1.z ^ te[s][6]);
            d += __popc(a1.w ^ te[s][7]);
            u32 key = ((u32)d << 16) | (u32)r;
            insert3(k0[s], k1[s], k2[s], key);
        }
    }
    #pragma unroll
    for (int s = 0; s < TT; ++s) {
        for (int off = 1; off < 64; off <<= 1) {
            u32 o0 = __shfl_xor(k0[s], off);
            u32 o1 = __shfl_xor(k1[s], off);
            u32 o2 = __shfl_xor(k2[s], off);
            merge3(k0[s], k1[s], k2[s], o0, o1, o2);
        }
    }
    __shared__ u32 red[4][TT][3];
    const int wave = tid >> 6, lane = tid & 63;
    if (lane == 0) {
        #pragma unroll
        for (int s = 0; s < TT; ++s) {
            red[wave][s][0] = k0[s];
            red[wave][s][1] = k1[s];
            red[wave][s][2] = k2[s];
        }
    }
    __syncthreads();
    if (tid < TT) {
        const int s = tid;
        u32 a0 = red[0][s][0], a1 = red[0][s][1], a2 = red[0][s][2];
        #pragma unroll
        for (int w = 1; w < 4; ++w)
            merge3(a0, a1, a2, red[w][s][0], red[w][s][1], red[w][s][2]);
        u32* dst = partial + ((size_t)(base + s) * NCHUNK + c) * 3;
        dst[0] = a0; dst[1] = a1; dst[2] = a2;
    }
}

__global__ __launch_bounds__(256) void merge_kernel(const u32* __restrict__ partial,
                                                    int* __restrict__ out) {
    int t = blockIdx.x * blockDim.x + threadIdx.x;
    if (t >= NUM_TEST) return;
    const u32* p = partial + (size_t)t * NCHUNK * 3;
    u32 a0 = p[0], a1 = p[1], a2 = p[2];
    #pragma unroll
    for (int c = 1; c < NCHUNK; ++c)
        merge3(a0, a1, a2, p[c * 3 + 0], p[c * 3 + 1], p[c * 3 + 2]);
    const int l0 = (int)(a0 & 0xFFFFu) / CLASS_SIZE;
    const int l1 = (int)(a1 & 0xFFFFu) / CLASS_SIZE;
    const int l2 = (int)(a2 & 0xFFFFu) / CLASS_SIZE;
    int winner;
    if (l0 == l1 || l0 == l2)      winner = l0;
    else if (l1 == l2)             winner = l1;
    else winner = min(l0, min(l1, l2));
    out[t] = winner;
}
// ===========================================================================

extern "C" void kernel_launch(void* const* d_in, const int* in_sizes, int n_in,
                              void* d_out, int out_size, void* d_ws, size_t ws_size,
                              hipStream_t stream) {
    const int* train = (const int*)d_in[0];
    const int* test  = (const int*)d_in[1];
    int* out = (int*)d_out;

    if (ws_size >= WS_NEED(32)) {
        char* train_i8 = (char*)d_ws;
        char* test_i8  = (char*)d_ws + OFF_TEST;
        int*  tesum    = (int*)((char*)d_ws + OFF_TESUM);
        u32*  partial  = (u32*)((char*)d_ws + OFF_PART);

        pack_train_bits<<<TRAIN_PAD / 4, 256, 0, stream>>>(train, train_i8);
        pack_test_pm1<<<NUM_TEST / 4, 256, 0, stream>>>(test, test_i8, tesum);
        if (ws_size >= WS_NEED(56)) {
            mfma_knn<56><<<32 * 56, 256, 0, stream>>>(train_i8, test_i8, tesum, partial);
            vote_knn<56><<<NUM_TEST / 256, 256, 0, stream>>>(partial, out);
        } else {
            mfma_knn<32><<<32 * 32, 256, 0, stream>>>(train_i8, test_i8, tesum, partial);
            vote_knn<32><<<NUM_TEST / 256, 256, 0, stream>>>(partial, out);
        }
    } else {
        // validated R5 path (1.93 MB ws)
        u64* packed = (u64*)d_ws;
        u32* partial = (u32*)((char*)d_ws + (size_t)(NUM_TRAIN + NUM_TEST) * 4 * sizeof(u64));
        const int total_rows = NUM_TRAIN + NUM_TEST;
        pack_kernel<<<total_rows / 4, 256, 0, stream>>>(train, test, packed);
        knn_kernel<<<(NUM_TEST / TT) * NCHUNK, 256, 0, stream>>>((const u32*)packed, partial);
        merge_kernel<<<(NUM_TEST + 255) / 256, 256, 0, stream>>>(partial, out);
    }
}

// Round 10
// 100.651 us; speedup vs baseline: 1.5785x; 1.0432x over previous
//
#include <hip/hip_runtime.h>
#include <stdint.h>

typedef unsigned long long u64;
typedef unsigned int u32;
typedef int v4i  __attribute__((ext_vector_type(4)));
typedef int v16i __attribute__((ext_vector_type(16)));

#define NUM_TRAIN   50000
#define NUM_TEST    4096
#define CLASS_SIZE  5000
#define TRAIN_PAD   50176              // 1568 tiles of 32 rows
#define TOT_TILES   1568

// ws layout: train_i8 | test_i8 | te_sum | partial
#define SZ_TRAIN   ((size_t)TRAIN_PAD * 256)          // 12,845,056
#define SZ_TEST    ((size_t)NUM_TEST * 256)           //  1,048,576
#define SZ_TESUM   ((size_t)NUM_TEST * 4)             //     16,384
#define OFF_TEST   (SZ_TRAIN)
#define OFF_TESUM  (OFF_TEST + SZ_TEST)
#define OFF_PART   (OFF_TESUM + SZ_TESUM)             // 13,910,016
#define WS_NEED(NCH) (OFF_PART + (size_t)NUM_TEST * (NCH) * 3 * 4)

// ---------------------------------------------------------------------------
// Top-3 primitives (validated R2/R5/R6/R9). key = (dist<<16)+train_idx
// encodes the reference (dist asc, then smaller index) tie-break exactly.
// ---------------------------------------------------------------------------
__device__ __forceinline__ void insert3(u32& k0, u32& k1, u32& k2, u32 key) {
    u32 m0 = min(k0, key);
    u32 m1 = min(k1, max(k0, key));
    u32 m2 = min(k2, max(k1, key));
    k0 = m0; k1 = m1; k2 = m2;
}
__device__ __forceinline__ void merge3(u32& a0, u32& a1, u32& a2,
                                       u32 b0, u32 b1, u32 b2) {
    u32 hi0 = max(a0, b0);
    u32 lo1 = min(a1, b1);
    u32 c0  = min(a0, b0);
    u32 c1  = min(hi0, lo1);
    u32 c2  = min(max(lo1, hi0), min(a2, b2));
    a0 = c0; a1 = c1; a2 = c2;
}
__device__ __forceinline__ int wave_sum(int s) {
    #pragma unroll
    for (int off = 1; off < 64; off <<= 1) s += __shfl_xor(s, off);
    return s;
}

// ---------------------------------------------------------------------------
// pack_train_bits: A byte = bit (0/1), 256 B/row. Pad rows (>=50000) zero.
// ---------------------------------------------------------------------------
__global__ __launch_bounds__(256) void pack_train_bits(const int* __restrict__ train,
                                                       char* __restrict__ dst) {
    int r    = (blockIdx.x * 256 + threadIdx.x) >> 6;
    int lane = threadIdx.x & 63;
    int4 v = make_int4(0, 0, 0, 0);
    if (r < NUM_TRAIN) v = *reinterpret_cast<const int4*>(train + (size_t)r * 256 + lane * 4);
    u32 w = (u32)(v.x & 1) | ((u32)(v.y & 1) << 8)
          | ((u32)(v.z & 1) << 16) | ((u32)(v.w & 1) << 24);
    *reinterpret_cast<u32*>(dst + (size_t)r * 256 + lane * 4) = w;
}

// pack_test_pm1: B byte = 1-2*bit (+1/-1); also writes te_sum[row].
__global__ __launch_bounds__(256) void pack_test_pm1(const int* __restrict__ test,
                                                     char* __restrict__ dst,
                                                     int* __restrict__ tesum) {
    int r    = (blockIdx.x * 256 + threadIdx.x) >> 6;
    int lane = threadIdx.x & 63;
    int4 v = *reinterpret_cast<const int4*>(test + (size_t)r * 256 + lane * 4);
    u32 w = (u32)((1 - 2 * v.x) & 0xFF) | ((u32)((1 - 2 * v.y) & 0xFF) << 8)
          | ((u32)((1 - 2 * v.z) & 0xFF) << 16) | ((u32)((1 - 2 * v.w) & 0xFF) << 24);
    *reinterpret_cast<u32*>(dst + (size_t)r * 256 + lane * 4) = w;
    int total = wave_sum(v.x + v.y + v.z + v.w);
    if (lane == 0) tesum[r] = total;
}

// ---------------------------------------------------------------------------
// mfma_knn: block (cg = bid/NCH, c = bid%NCH). 4 waves share one 32-row
// A-tile in LDS; each wave owns 64 test cols (two B-frag sets in regs), so
// each ds_read feeds TWO MFMAs (halved LDS traffic per unit work).
//
// LDS layout (conflict-free by construction): fragment (kk,kh,row) at
//   kk*1024 + kh*512 + ((row^kk)&31)*16.
// Reads (fixed kk): lane batch 0-7 reads slots (a^kk) -> 8 distinct slot%8
// residues (XOR by const permutes 0..7) -> conflict-free. Writes: batch
// lanes 0-7 share row r with kk=0..7 -> slots kk*64+(r^kk) -> residues
// (r^kk)&7 distinct -> conflict-free. Staging global load (t*32) coalesced.
//
// acc = tr_sum - 2*inner; dist = acc + te_sum folded into the key base.
// Guarded epilogue nulls pad rows (idx >= 50000) on boundary tiles only.
// ---------------------------------------------------------------------------
template<int NCH>
__global__ __launch_bounds__(256) void mfma_knn(const char* __restrict__ A,
                                                const char* __restrict__ Bt,
                                                const int* __restrict__ tesum,
                                                u32* __restrict__ partial) {
    constexpr int TILES  = TOT_TILES / NCH;    // 28 (NCH=56) or 49 (NCH=32)
    constexpr int CHROWS = TRAIN_PAD / NCH;    // 896 or 1568
    const int cg   = blockIdx.x / NCH;
    const int c    = blockIdx.x % NCH;
    const int tid  = threadIdx.x;
    const int wid  = tid >> 6;
    const int lane = tid & 63;
    const int a    = lane & 31;                // A-row within tile / B-col lane
    const int kh   = lane >> 5;                // K-half

    // Two B-fragment sets: this wave's 64 test cols, 8 K-steps, in registers.
    const int col0 = cg * 256 + wid * 64 + a;
    const int col1 = col0 + 32;
    v4i bf0[8], bf1[8];
    {
        const char* bp0 = Bt + (size_t)col0 * 256 + kh * 16;
        const char* bp1 = Bt + (size_t)col1 * 256 + kh * 16;
        #pragma unroll
        for (int kk = 0; kk < 8; ++kk) {
            bf0[kk] = *reinterpret_cast<const v4i*>(bp0 + kk * 32);
            bf1[kk] = *reinterpret_cast<const v4i*>(bp1 + kk * 32);
        }
    }
    const u32 base0 = ((u32)tesum[col0] << 16);   // te_sum folded into key
    const u32 base1 = ((u32)tesum[col1] << 16);

    __shared__ char lds[8192];
    // tile-invariant read addresses (one per kk)
    char* rd[8];
    #pragma unroll
    for (int kk = 0; kk < 8; ++kk)
        rd[kk] = &lds[kk * 1024 + kh * 512 + ((a ^ kk) & 31) * 16];

    // staging: thread t loads row grow bytes [gc*32, +32) (coalesced t*32)
    const int grow = tid >> 3, gc = tid & 7;
    const char* gsrc0 = A + (size_t)c * CHROWS * 256 + grow * 256 + gc * 32;
    char* w0 = &lds[gc * 1024 +       ((grow ^ gc) & 31) * 16];   // kh=0 half
    char* w1 = &lds[gc * 1024 + 512 + ((grow ^ gc) & 31) * 16];   // kh=1 half

    u32 p00 = 0x7FFFFFFFu, p01 = 0x7FFFFFFFu, p02 = 0x7FFFFFFFu;
    u32 p10 = 0x7FFFFFFFu, p11 = 0x7FFFFFFFu, p12 = 0x7FFFFFFFu;

    // prologue: stage tile 0
    uint4 s0 = *reinterpret_cast<const uint4*>(gsrc0);
    uint4 s1 = *reinterpret_cast<const uint4*>(gsrc0 + 16);
    *reinterpret_cast<uint4*>(w0) = s0;
    *reinterpret_cast<uint4*>(w1) = s1;
    __syncthreads();

    for (int t = 0; t < TILES; ++t) {
        if (t + 1 < TILES) {               // issue next-tile loads early (T14)
            const char* g = gsrc0 + (size_t)(t + 1) * 8192;
            s0 = *reinterpret_cast<const uint4*>(g);
            s1 = *reinterpret_cast<const uint4*>(g + 16);
        }
        v16i acc0 = {0,0,0,0,0,0,0,0,0,0,0,0,0,0,0,0};
        v16i acc1 = {0,0,0,0,0,0,0,0,0,0,0,0,0,0,0,0};
        #pragma unroll
        for (int kk = 0; kk < 8; ++kk) {
            v4i af = *reinterpret_cast<const v4i*>(rd[kk]);
            acc0 = __builtin_amdgcn_mfma_i32_32x32x32_i8(af, bf0[kk], acc0, 0, 0, 0);
            acc1 = __builtin_amdgcn_mfma_i32_32x32x32_i8(af, bf1[kk], acc1, 0, 0, 0);
        }
        const int tbase = c * CHROWS + t * 32;
        const u32 kb0 = base0 + (u32)(tbase + 4 * kh);
        const u32 kb1 = base1 + (u32)(tbase + 4 * kh);
        if (tbase + 32 <= NUM_TRAIN) {               // uniform fast path
            #pragma unroll
            for (int g = 0; g < 16; ++g) {
                const int row = (g & 3) + 8 * (g >> 2);
                insert3(p00, p01, p02, ((u32)acc0[g] << 16) + kb0 + (u32)row);
                insert3(p10, p11, p12, ((u32)acc1[g] << 16) + kb1 + (u32)row);
            }
        } else {                                     // boundary/pad tiles only
            #pragma unroll
            for (int g = 0; g < 16; ++g) {
                const int row = (g & 3) + 8 * (g >> 2);
                const int idx = tbase + 4 * kh + row;
                u32 key0 = (idx < NUM_TRAIN)
                             ? (((u32)acc0[g] << 16) + kb0 + (u32)row) : 0xFFFFFFFFu;
                u32 key1 = (idx < NUM_TRAIN)
                             ? (((u32)acc1[g] << 16) + kb1 + (u32)row) : 0xFFFFFFFFu;
                insert3(p00, p01, p02, key0);
                insert3(p10, p11, p12, key1);
            }
        }
        __syncthreads();                   // all waves done reading LDS(t)
        if (t + 1 < TILES) {
            *reinterpret_cast<uint4*>(w0) = s0;
            *reinterpret_cast<uint4*>(w1) = s1;
        }
        __syncthreads();                   // LDS holds tile t+1
    }

    // lanes l / l+32 hold complementary row-halves of the same test col
    u32 o0, o1, o2;
    o0 = __shfl_xor(p00, 32); o1 = __shfl_xor(p01, 32); o2 = __shfl_xor(p02, 32);
    merge3(p00, p01, p02, o0, o1, o2);
    o0 = __shfl_xor(p10, 32); o1 = __shfl_xor(p11, 32); o2 = __shfl_xor(p12, 32);
    merge3(p10, p11, p12, o0, o1, o2);
    if (kh == 0) {
        u32* d0 = partial + ((size_t)col0 * NCH + c) * 3;
        d0[0] = p00; d0[1] = p01; d0[2] = p02;
        u32* d1 = partial + ((size_t)col1 * NCH + c) * 3;
        d1[0] = p10; d1[1] = p11; d1[2] = p12;
    }
}

// Vote kernel: merge NCH partial triples per sample; majority vote with
// argmax-first-max tie semantics (validated R2/R5/R6/R9).
template<int NCH>
__global__ __launch_bounds__(256) void vote_knn(const u32* __restrict__ partial,
                                                int* __restrict__ out) {
    int t = blockIdx.x * 256 + threadIdx.x;
    if (t >= NUM_TEST) return;
    const u32* p = partial + (size_t)t * NCH * 3;
    u32 a0 = p[0], a1 = p[1], a2 = p[2];
    for (int c = 1; c < NCH; ++c)
        merge3(a0, a1, a2, p[c * 3 + 0], p[c * 3 + 1], p[c * 3 + 2]);
    const int l0 = (int)(a0 & 0xFFFFu) / CLASS_SIZE;
    const int l1 = (int)(a1 & 0xFFFFu) / CLASS_SIZE;
    const int l2 = (int)(a2 & 0xFFFFu) / CLASS_SIZE;
    int winner;
    if (l0 == l1 || l0 == l2)      winner = l0;
    else if (l1 == l2)             winner = l1;
    else winner = min(l0, min(l1, l2));
    out[t] = winner;
}

// ======================= validated R5 fallback path ========================
#define TT          8
#define NCHUNK      4
#define CHUNK_ROWS  (NUM_TRAIN / NCHUNK)

__global__ void pack_kernel(const int* __restrict__ train,
                            const int* __restrict__ test,
                            u64* __restrict__ packed) {
    int wave = (blockIdx.x * blockDim.x + threadIdx.x) >> 6;
    int lane = threadIdx.x & 63;
    const int* src = (wave < NUM_TRAIN)
                       ? (train + (size_t)wave * 256)
                       : (test + (size_t)(wave - NUM_TRAIN) * 256);
    int4 v = *reinterpret_cast<const int4*>(src + lane * 4);
    u64 b0 = __ballot(v.x & 1);
    u64 b1 = __ballot(v.y & 1);
    u64 b2 = __ballot(v.z & 1);
    u64 b3 = __ballot(v.w & 1);
    if (lane == 0) {
        u64* dst = packed + (size_t)wave * 4;
        dst[0] = b0; dst[1] = b1; dst[2] = b2; dst[3] = b3;
    }
}

__global__ __launch_bounds__(256) void knn_kernel(const u32* __restrict__ packed,
                                                  u32* __restrict__ partial) {
    const int g    = blockIdx.x >> 2;
    const int c    = blockIdx.x & 3;
    const int tid  = threadIdx.x;
    const int base = g * TT;
    const uint4* rows  = (const uint4*)packed;
    const u32*  testp  = packed + (size_t)NUM_TRAIN * 8;

    u32 te[TT][8];
    #pragma unroll
    for (int s = 0; s < TT; ++s) {
        const u32* p = testp + (size_t)(base + s) * 8;
        #pragma unroll
        for (int j = 0; j < 8; ++j) te[s][j] = p[j];
    }
    u32 k0[TT], k1[TT], k2[TT];
    #pragma unroll
    for (int s = 0; s < TT; ++s) { k0[s] = k1[s] = k2[s] = 0x7FFFFFFFu; }

    const int start = c * CHUNK_ROWS;
    const int end   = start + CHUNK_ROWS;
    for (int r = start + tid; r < end; r += 256) {
        uint4 a0 = rows[(size_t)r * 2];
        uint4 a1 = rows[(size_t)r * 2 + 1];
        #pragma unroll
        for (int s = 0; s < TT; ++s) {
            int d = __popc(a0.x ^ te[s][0]);
            d += __popc(a0.y ^ te[s][1]);
            d += __popc(a0.z ^ te[s][2]);
            d += __popc(a0.w ^ te[s][3]);
            d += __popc(a1.x ^ te[s][4]);
            d += __popc(a1.y ^ te[s][5]);
            d += __popc(a1.z ^ te[s][6]);
            d += __popc(a1.w ^ te[s][7]);
            u32 key = ((u32)d << 16) | (u32)r;
            insert3(k0[s], k1[s], k2[s], key);
        }
    }
    #pragma unroll
    for (int s = 0; s < TT; ++s) {
        for (int off = 1; off < 64; off <<= 1) {
            u32 o0 = __shfl_xor(k0[s], off);
            u32 o1 = __shfl_xor(k1[s], off);
            u32 o2 = __shfl_xor(k2[s], off);
            merge3(k0[s], k1[s], k2[s], o0, o1, o2);
        }
    }
    __shared__ u32 red[4][TT][3];
    const int wave = tid >> 6, lane = tid & 63;
    if (lane == 0) {
        #pragma unroll
        for (int s = 0; s < TT; ++s) {
            red[wave][s][0] = k0[s];
            red[wave][s][1] = k1[s];
            red[wave][s][2] = k2[s];
        }
    }
    __syncthreads();
    if (tid < TT) {
        const int s = tid;
        u32 a0 = red[0][s][0], a1 = red[0][s][1], a2 = red[0][s][2];
        #pragma unroll
        for (int w = 1; w < 4; ++w)
            merge3(a0, a1, a2, red[w][s][0], red[w][s][1], red[w][s][2]);
        u32* dst = partial + ((size_t)(base + s) * NCHUNK + c) * 3;
        dst[0] = a0; dst[1] = a1; dst[2] = a2;
    }
}

__global__ __launch_bounds__(256) void merge_kernel(const u32* __restrict__ partial,
                                                    int* __restrict__ out) {
    int t = blockIdx.x * blockDim.x + threadIdx.x;
    if (t >= NUM_TEST) return;
    const u32* p = partial + (size_t)t * NCHUNK * 3;
    u32 a0 = p[0], a1 = p[1], a2 = p[2];
    #pragma unroll
    for (int c = 1; c < NCHUNK; ++c)
        merge3(a0, a1, a2, p[c * 3 + 0], p[c * 3 + 1], p[c * 3 + 2]);
    const int l0 = (int)(a0 & 0xFFFFu) / CLASS_SIZE;
    const int l1 = (int)(a1 & 0xFFFFu) / CLASS_SIZE;
    const int l2 = (int)(a2 & 0xFFFFu) / CLASS_SIZE;
    int winner;
    if (l0 == l1 || l0 == l2)      winner = l0;
    else if (l1 == l2)             winner = l1;
    else winner = min(l0, min(l1, l2));
    out[t] = winner;
}
// ===========================================================================

extern "C" void kernel_launch(void* const* d_in, const int* in_sizes, int n_in,
                              void* d_out, int out_size, void* d_ws, size_t ws_size,
                              hipStream_t stream) {
    const int* train = (const int*)d_in[0];
    const int* test  = (const int*)d_in[1];
    int* out = (int*)d_out;

    if (ws_size >= WS_NEED(32)) {
        char* train_i8 = (char*)d_ws;
        char* test_i8  = (char*)d_ws + OFF_TEST;
        int*  tesum    = (int*)((char*)d_ws + OFF_TESUM);
        u32*  partial  = (u32*)((char*)d_ws + OFF_PART);

        pack_train_bits<<<TRAIN_PAD / 4, 256, 0, stream>>>(train, train_i8);
        pack_test_pm1<<<NUM_TEST / 4, 256, 0, stream>>>(test, test_i8, tesum);
        if (ws_size >= WS_NEED(56)) {
            mfma_knn<56><<<16 * 56, 256, 0, stream>>>(train_i8, test_i8, tesum, partial);
            vote_knn<56><<<NUM_TEST / 256, 256, 0, stream>>>(partial, out);
        } else {
            mfma_knn<32><<<16 * 32, 256, 0, stream>>>(train_i8, test_i8, tesum, partial);
            vote_knn<32><<<NUM_TEST / 256, 256, 0, stream>>>(partial, out);
        }
    } else {
        // validated R5 path (1.93 MB ws)
        u64* packed = (u64*)d_ws;
        u32* partial = (u32*)((char*)d_ws + (size_t)(NUM_TRAIN + NUM_TEST) * 4 * sizeof(u64));
        const int total_rows = NUM_TRAIN + NUM_TEST;
        pack_kernel<<<total_rows / 4, 256, 0, stream>>>(train, test, packed);
        knn_kernel<<<(NUM_TEST / TT) * NCHUNK, 256, 0, stream>>>((const u32*)packed, partial);
        merge_kernel<<<(NUM_TEST + 255) / 256, 256, 0, stream>>>(partial, out);
    }
}